// Round 2
// baseline (108.138 us; speedup 1.0000x reference)
//
#include <hip/hip_runtime.h>
#include <math.h>

// ws layout (floats):
//   terms: [0, 6144)    512*12: {-Lr, Li, t0r,t0i, t1r,t1i, t2r,t2i, t3r,t3i, Lr^2, t2s}
//   ZT:    [8192, +131072)  single plane of 65536 float2: ZT[t1*256 + l1]
constexpr int WS_TERMS = 0;
constexpr int WS_ZT    = 8192;

__device__ __forceinline__ float sin2pi(float x) { return __builtin_amdgcn_sinf(x); }
__device__ __forceinline__ float cos2pi(float x) { return __builtin_amdgcn_cosf(x); }

// ---------------------------------------------------------------------------
// Kernel 1: per-n setup.  Bc = Vc @ B (complex); terms in r12 format.
__global__ __launch_bounds__(256) void k_setup(
    const float* __restrict__ Lr, const float* __restrict__ Li,
    const float* __restrict__ pr, const float* __restrict__ pi,
    const float* __restrict__ qr, const float* __restrict__ qi,
    const float* __restrict__ Vr, const float* __restrict__ Vi,
    const float* __restrict__ Ct, const float* __restrict__ Bv,
    const float* __restrict__ log_step,
    float* __restrict__ terms)
{
    __shared__ float red[8];
    int n = blockIdx.x;
    int t = threadIdx.x;
    float b0 = Bv[t], b1 = Bv[t + 256];
    float sr = fmaf(Vr[n*512 + t], b0, Vr[n*512 + t + 256] * b1);
    float si = fmaf(Vi[n*512 + t], b0, Vi[n*512 + t + 256] * b1);
    #pragma unroll
    for (int off = 32; off > 0; off >>= 1) {
        sr += __shfl_down(sr, off, 64);
        si += __shfl_down(si, off, 64);
    }
    if ((t & 63) == 0) { red[(t >> 6)*2] = sr; red[(t >> 6)*2 + 1] = si; }
    __syncthreads();
    if (t == 0) {
        float b0r = red[0] + red[2] + red[4] + red[6];
        float b0i = red[1] + red[3] + red[5] + red[7];
        double step = exp((double)log_step[0]);
        float t2s = (float)(2.0 / step);
        float lr  = Lr[n];
        float a0r = Ct[2*n], a0i = -Ct[2*n+1];   // conj(Ct_c)
        float a1r = qr[n],   a1i = -qi[n];       // conj(q)
        float b1r = pr[n],   b1i = pi[n];        // p
        float* tm = terms + n * 12;
        tm[0]  = -lr;                 tm[1]  = Li[n];
        tm[2]  = a0r*b0r - a0i*b0i;   tm[3]  = a0r*b0i + a0i*b0r;
        tm[4]  = a0r*b1r - a0i*b1i;   tm[5]  = a0r*b1i + a0i*b1r;
        tm[6]  = a1r*b0r - a1i*b0i;   tm[7]  = a1r*b0i + a1i*b0r;
        tm[8]  = a1r*b1r - a1i*b1i;   tm[9]  = a1r*b1i + a1i*b1r;
        tm[10] = lr*lr;               tm[11] = t2s;
    }
}

// ---------------------------------------------------------------------------
// Kernel 2: Cauchy + resolvent + full stage-A DFT for one l1 column.
// 256 blocks x 512 threads; block = l1.  Thread (u = tid&63, chunk = tid>>6):
// FOUR l2 values {u, u+64, u+128, u+192} x n in [chunk*64, chunk*64+64).
// Rationale: terms reads are wave-uniform broadcasts; their count scales with
// wave count.  4 l per thread cuts waves 8192->2048, so total broadcast
// b128 reads drop 4x (per-CU: 8 waves x 192 x ~12cyc = 7.7us, under the
// ~10us VALU floor).  One block produces ALL 256 l2 for its l1, so the 4
// quarter-planes fold in registers and we write ONE summed ZT plane.
// LDS: terms[6144] | planes[4][64][9]=2304 @6144 | red[64][9]=576 @8448
//      xrow float2[64] @0 (overlay, post-loop) | partA float2[512] @128
__global__ __launch_bounds__(512) void k_mainA(
    const float* __restrict__ terms,
    float* __restrict__ ZTf)
{
    __shared__ float buf[9024];   // 36.1 KB -> 1 block/CU (grid==CU count)
    int tid = threadIdx.x;
    int l1  = blockIdx.x;

    // ---- stage terms -> LDS (1536 float4, 3 per thread, coalesced)
    {
        float4* dst = (float4*)buf;
        const float4* src = (const float4*)terms;
        #pragma unroll
        for (int i = 0; i < 3; ++i) dst[tid + 512*i] = src[tid + 512*i];
    }

    int u     = tid & 63;
    int chunk = tid >> 6;              // wave-uniform

    float t2s = terms[11];             // uniform load (L1/L2 hit)

    float T[4], g_i[4];
    #pragma unroll
    for (int q = 0; q < 4; ++q) {
        int l = l1 + 256*(u + 64*q);
        float tv2 = (float)l * (1.0f / 131072.0f);   // exact fp32 fraction
        float sn  = sin2pi(tv2), cn = cos2pi(tv2);
        float Tq  = sn / cn;                          // tan(pi*l/L)
        float gq  = t2s * Tq;
        // pole l = L/2: legit |T| <= ~2.1e4; bigger is the pole -> r=0, c~=1
        if (!(fabsf(Tq) <= 1.0e6f)) { gq = 3e30f; Tq = 0.f; }
        T[q] = Tq; g_i[q] = gq;
    }
    __syncthreads();                              // staging visible

    float ac[4][8];
    #pragma unroll
    for (int q = 0; q < 4; ++q)
        #pragma unroll
        for (int c = 0; c < 8; ++c) ac[q][c] = 0.f;

    const float4* t4 = (const float4*)buf + chunk * 64 * 3;
    #pragma unroll 2
    for (int n = 0; n < 64; ++n) {
        float4 Aq = t4[n*3 + 0];   // -Lr, Li, t0r, t0i  (broadcast ds_read_b128)
        float4 Bq = t4[n*3 + 1];   // t1r, t1i, t2r, t2i
        float4 Cq = t4[n*3 + 2];   // t3r, t3i, Lr^2, t2s
        #pragma unroll
        for (int q = 0; q < 4; ++q) {
            float di = g_i[q] - Aq.y;
            float dd = fmaf(di, di, Cq.z);       // di^2 + Lr^2; inf at pole -> r=0
            float iv = __builtin_amdgcn_rcpf(dd);
            float rr = Aq.x * iv;                // (-Lr)/dd
            float ri = -di * iv;
            ac[q][0] = fmaf(rr, Aq.z, ac[q][0]); ac[q][0] = fmaf(-ri, Aq.w, ac[q][0]);
            ac[q][1] = fmaf(rr, Aq.w, ac[q][1]); ac[q][1] = fmaf( ri, Aq.z, ac[q][1]);
            ac[q][2] = fmaf(rr, Bq.x, ac[q][2]); ac[q][2] = fmaf(-ri, Bq.y, ac[q][2]);
            ac[q][3] = fmaf(rr, Bq.y, ac[q][3]); ac[q][3] = fmaf( ri, Bq.x, ac[q][3]);
            ac[q][4] = fmaf(rr, Bq.z, ac[q][4]); ac[q][4] = fmaf(-ri, Bq.w, ac[q][4]);
            ac[q][5] = fmaf(rr, Bq.w, ac[q][5]); ac[q][5] = fmaf( ri, Bq.z, ac[q][5]);
            ac[q][6] = fmaf(rr, Cq.x, ac[q][6]); ac[q][6] = fmaf(-ri, Cq.y, ac[q][6]);
            ac[q][7] = fmaf(rr, Cq.y, ac[q][7]); ac[q][7] = fmaf( ri, Cq.x, ac[q][7]);
        }
    }
    __syncthreads();   // terms reads done; terms LDS region reusable

    float accR = 0.f, accI = 0.f;     // per-(t1=tid<256) sum over quarters

    #pragma unroll
    for (int q = 0; q < 4; ++q) {
        // ---- fold 8 n-chunks -> 4 planes (chunks 4..7 write, 0..3 accumulate)
        if (chunk >= 4) {
            float* p = buf + 6144 + (chunk - 4) * 576 + u * 9;
            #pragma unroll
            for (int c = 0; c < 8; ++c) p[c] = ac[q][c];
        }
        __syncthreads();
        if (chunk < 4) {
            float* p = buf + 6144 + chunk * 576 + u * 9;
            #pragma unroll
            for (int c = 0; c < 8; ++c) p[c] += ac[q][c];
        }
        __syncthreads();

        // ---- stage-1: 512 slots (64 l2-local x 8 comp) -> red @8448
        {
            int a = (tid >> 3) * 9 + (tid & 7);
            buf[8448 + a] = buf[6144 + a] + buf[6720 + a] + buf[7296 + a] + buf[7872 + a];
        }
        __syncthreads();

        // ---- stage-2: atRoots for l2 = 64q + tid (tid<64); own T[q] (u=tid, chunk=0)
        if (tid < 64) {
            const float* rd = buf + 8448 + tid * 9;
            float s0r = rd[0], s0i = rd[1], s1r = rd[2], s1i = rd[3];
            float s2r = rd[4], s2i = rd[5], s3r = rd[6], s3i = rd[7];
            float e1r = 1.f + s3r, e1i = s3i;
            float eiv = 1.0f / fmaf(e1r, e1r, e1i * e1i);
            float m_r = s1r * s2r - s1i * s2i;
            float m_i = s1r * s2i + s1i * s2r;
            float q_r = (m_r * e1r + m_i * e1i) * eiv;
            float q_i = (m_i * e1r - m_r * e1i) * eiv;
            float u_r = s0r - q_r;
            float u_i = s0i - q_i;
            float Tq  = T[q];
            ((float2*)buf)[tid] = make_float2(u_r - Tq * u_i, u_i + Tq * u_r); // xrow @0
        }
        __syncthreads();

        // ---- partial DFT-A over this quarter's 64 l2 (2-way split)
        {
            int t1 = tid & 255;
            int s  = tid >> 8;            // 0..1, wave-uniform
            int j0 = s * 32;
            int mm0 = ((q*64 + j0) * t1) & 255;
            float curR = cos2pi((float)mm0 * (1.0f/256.0f));
            float curI = sin2pi((float)mm0 * (1.0f/256.0f));
            float rotR = cos2pi((float)t1 * (1.0f/256.0f));
            float rotI = sin2pi((float)t1 * (1.0f/256.0f));
            const float2* xrow = (const float2*)buf;
            float yr = 0.f, yi = 0.f;
            #pragma unroll 8
            for (int j = j0; j < j0 + 32; ++j) {
                float2 x = xrow[j];   // broadcast
                yr = fmaf(x.x, curR, yr); yr = fmaf(-x.y, curI, yr);
                yi = fmaf(x.x, curI, yi); yi = fmaf( x.y, curR, yi);
                float nR = curR * rotR - curI * rotI;
                float nI = curR * rotI + curI * rotR;
                curR = nR; curI = nI;
            }
            ((float2*)(buf + 128))[tid] = make_float2(yr, yi);   // partA @128
        }
        __syncthreads();
        if (tid < 256) {
            const float2* pA = (const float2*)(buf + 128);
            float2 p0 = pA[tid], p1 = pA[tid + 256];
            accR += p0.x + p1.x;
            accI += p0.y + p1.y;
        }
        // next q's fold writes planes @6144+ (disjoint from partA @128..1152,
        // last read above) and is separated from stage-1's plane reads by >=2
        // barriers -> no extra barrier needed here.
    }

    // ---- W_L twiddle + single summed plane write
    if (tid < 256) {
        int mm = (l1 * tid) & 65535;
        float tv = (float)mm * (1.0f / 65536.0f);
        float twR = cos2pi(tv), twI = sin2pi(tv);
        ((float2*)ZTf)[tid * 256 + l1] =
            make_float2(accR * twR - accI * twI, accR * twI + accI * twR);
    }
}

// ---------------------------------------------------------------------------
// Kernel 3: DFT-B.  1024 blocks x 256 threads; block = (t1 = b>>2, qT = b&3)
// covers t2 in [qT*64, qT*64+64).  zrow = single (pre-summed) ZT plane row.
__global__ __launch_bounds__(256) void k_fftB(
    const float* __restrict__ ZTf, float* __restrict__ out)
{
    __shared__ float buf2[768];    // zrow float2[256] @0, partB[256] @512
    int tid = threadIdx.x;
    int b   = blockIdx.x;
    int t1 = b >> 2;
    int qT = b & 3;
    {
        float2 v = ((const float2*)ZTf)[t1 * 256 + tid];
        ((float2*)buf2)[tid] = v;
    }
    int k2 = tid & 63;
    int s  = tid >> 6;            // 0..3, wave-uniform
    int t2 = qT * 64 + k2;
    int m0 = (s * t2) & 3;
    float curR = (m0 == 0) ? 1.f : (m0 == 2 ? -1.f : 0.f);
    float curI = (m0 == 1) ? 1.f : (m0 == 3 ? -1.f : 0.f);
    float rotR = cos2pi((float)t2 * (1.0f / 256.0f));
    float rotI = sin2pi((float)t2 * (1.0f / 256.0f));
    __syncthreads();
    const float2* zrow = (const float2*)buf2;
    float o = 0.f;
    #pragma unroll 8
    for (int j = s * 64; j < s * 64 + 64; ++j) {
        float2 z = zrow[j];   // broadcast
        o = fmaf(z.x, curR, o);
        o = fmaf(-z.y, curI, o);
        float nR = curR * rotR - curI * rotI;
        float nI = curR * rotI + curI * rotR;
        curR = nR; curI = nI;
    }
    buf2[512 + tid] = o;
    __syncthreads();
    if (tid < 64) {
        float sum = buf2[512+tid] + buf2[512+tid+64] + buf2[512+tid+128] + buf2[512+tid+192];
        out[t1 + 256 * (qT * 64 + tid)] = sum * (1.0f / 65536.0f);
    }
}

// ---------------------------------------------------------------------------
extern "C" void kernel_launch(void* const* d_in, const int* in_sizes, int n_in,
                              void* d_out, int out_size, void* d_ws, size_t ws_size,
                              hipStream_t stream)
{
    const float* Lambda_re = (const float*)d_in[0];
    const float* Lambda_im = (const float*)d_in[1];
    const float* p_re      = (const float*)d_in[2];
    const float* p_im      = (const float*)d_in[3];
    const float* q_re      = (const float*)d_in[4];
    const float* q_im      = (const float*)d_in[5];
    const float* Vc_re     = (const float*)d_in[6];
    const float* Vc_im     = (const float*)d_in[7];
    const float* Ct        = (const float*)d_in[8];
    const float* Bv        = (const float*)d_in[9];
    const float* log_step  = (const float*)d_in[10];

    float* wsf   = (float*)d_ws;
    float* terms = wsf + WS_TERMS;
    float* ZT    = wsf + WS_ZT;
    float* outp  = (float*)d_out;

    k_setup<<<512, 256, 0, stream>>>(Lambda_re, Lambda_im, p_re, p_im, q_re, q_im,
                                     Vc_re, Vc_im, Ct, Bv, log_step, terms);
    k_mainA<<<256, 512, 0, stream>>>(terms, ZT);
    k_fftB<<<1024, 256, 0, stream>>>(ZT, outp);
}